// Round 5
// baseline (646.621 us; speedup 1.0000x reference)
//
#include <hip/hip_runtime.h>
#include <hip/hip_bf16.h>

// out[M,N] = X[M,K] @ W[K,N] + (X@A)@B + bias;  M=16384, N=K=4096.
// P1: X -> bf16.  P2: Wt[n][k] = bf16(W[k][n] + lora).
// G: 256x256 tile, 8 waves (2x4), mfma_f32_32x32x16_bf16, 2 phases per K-tile(64).

typedef __attribute__((ext_vector_type(8))) __bf16 bf16x8;
typedef __attribute__((ext_vector_type(4))) float f32x4;
typedef __attribute__((ext_vector_type(16))) float f32x16;

#define M_DIM 16384
#define N_DIM 4096
#define K_DIM 4096

__device__ __forceinline__ void async16(const void* g, void* l) {
    __builtin_amdgcn_global_load_lds((const __attribute__((address_space(1))) void*)g,
                                     (__attribute__((address_space(3))) void*)l,
                                     16, 0, 0);
}

// ---------------- P1: cast X to bf16 ----------------
__global__ void cast_x_kernel(const float* __restrict__ x, __bf16* __restrict__ xb, size_t n) {
    size_t i0 = ((size_t)blockIdx.x * blockDim.x + threadIdx.x) * 8;
    size_t stride = (size_t)gridDim.x * blockDim.x * 8;
    for (size_t i = i0; i < n; i += stride) {
        f32x4 v0 = __builtin_nontemporal_load((const f32x4*)(x + i));
        f32x4 v1 = __builtin_nontemporal_load((const f32x4*)(x + i + 4));
        bf16x8 o;
        o[0] = (__bf16)v0[0]; o[1] = (__bf16)v0[1]; o[2] = (__bf16)v0[2]; o[3] = (__bf16)v0[3];
        o[4] = (__bf16)v1[0]; o[5] = (__bf16)v1[1]; o[6] = (__bf16)v1[2]; o[7] = (__bf16)v1[3];
        *(bf16x8*)(xb + i) = o;
    }
}

// ---------------- P2: Wt[n][k] = bf16(W[k][n] + lora) ----------------
__global__ void prep_w_kernel(const float* __restrict__ W, const float* __restrict__ A,
                              const float* __restrict__ Bm, __bf16* __restrict__ Wt) {
    __shared__ float Ws[32][33];
    __shared__ float As[32][16];
    __shared__ float Bs[16][32];
    const int tx = threadIdx.x;
    const int ty = threadIdx.y;
    const int t = ty * 32 + tx;
    const int n0 = blockIdx.x * 32;
    const int k0 = blockIdx.y * 32;

#pragma unroll
    for (int i = 0; i < 4; ++i) {
        int k = ty + i * 8;
        Ws[k][tx] = W[(size_t)(k0 + k) * N_DIM + n0 + tx];
    }
    for (int i = t; i < 512; i += 256)
        As[i >> 4][i & 15] = A[(size_t)(k0 + (i >> 4)) * 16 + (i & 15)];
    for (int i = t; i < 512; i += 256)
        Bs[i >> 5][i & 31] = Bm[(size_t)(i >> 5) * N_DIM + n0 + (i & 31)];
    __syncthreads();

    float a[16];
#pragma unroll
    for (int r = 0; r < 16; ++r) a[r] = As[tx][r];
#pragma unroll
    for (int i = 0; i < 4; ++i) {
        int n = ty + i * 8;
        float acc = Ws[tx][n];
#pragma unroll
        for (int r = 0; r < 16; ++r) acc += a[r] * Bs[r][n];
        Wt[(size_t)(n0 + n) * K_DIM + k0 + tx] = (__bf16)acc;
    }
}

// ---------------- G: 256x256 2-phase/K-tile 32x32x16 MFMA GEMM ----------------
// 512 threads = 8 waves (2 wr x 4 wn). Per wave 128x64 out = 4 m-tiles x 2 n-tiles of 32x32.
// LDS: 2 bufs x (A[256][64] + B[256][64]) bf16 = 128 KiB, col-swizzle byte ^= ((row&7)<<4).
// B rows stored nt-permuted: phys p = nt*128 + wn*32 + s  <->  logical n = wn*64 + nt*32 + s.
// Phase P0(t): reads A rows {0-63,128-191} (m-tiles 0,1 per wr) + ALL B (frags held in regs).
// Phase P1(t): reads A rows {64-127,192-255} (m-tiles 2,3), B reused from registers.
// Stage slots: P0(t): A(t+1)->other buf [HT0: rows 0,128; HT1: rows 64,192].
//              P1(t): B(t+2)->current buf [rows 0,64,128,192]  (B(t) fully consumed end-P0(t)).
// FIFO vmcnt ledger (4 loads/slot): end-P0: vmcnt(8) drains A-HT1(t);
//   end-P1: vmcnt(6) drains B(t+1)+A-HT0(t+1); invariant left = {A-HT1(t+1)x2, B(t+2)x4}.

#define WAIT_VM(N) asm volatile("s_waitcnt vmcnt(" #N ")" ::: "memory")
#define BARRIER() do { asm volatile("" ::: "memory"); __builtin_amdgcn_s_barrier(); asm volatile("" ::: "memory"); } while (0)

#define STAGE_A(ldsbase, row0, kt) do {                                              \
    int r_ = (row0) + srow;                                                          \
    async16(Xb + (size_t)(m0 + r_) * K_DIM + (kt) + scol,                            \
            (ldsbase) + (row0) * 128 + sldsoff); } while (0)

#define STAGE_B(ldsbase, row0, kt) do {                                              \
    int p_ = (row0) + srow;                                                          \
    int nl_ = ((p_ >> 5) & 3) * 64 + ((p_ >> 7) & 1) * 32 + (p_ & 31);               \
    async16(Wt + (size_t)(n0 + nl_) * K_DIM + (kt) + scol,                           \
            (ldsbase) + (row0) * 128 + sldsoff); } while (0)

#define DS_A(buf, MTG, KC) (*(const bf16x8*)((buf) + aRow32 + (MTG) * 4096 + colswk[KC]))
#define DS_B(buf, NT, KC)  (*(const bf16x8*)((buf) + bRow32 + (NT) * 16384 + colswk[KC]))

#define P0_CORE(AC, BC)                                                              \
    _Pragma("unroll") for (int mt_ = 0; mt_ < 2; ++mt_)                              \
    _Pragma("unroll") for (int kc_ = 0; kc_ < 4; ++kc_)                              \
        afr[mt_][kc_] = DS_A(AC, mt_, kc_);                                          \
    _Pragma("unroll") for (int nt_ = 0; nt_ < 2; ++nt_)                              \
    _Pragma("unroll") for (int kc_ = 0; kc_ < 4; ++kc_)                              \
        bfr[nt_][kc_] = DS_B(BC, nt_, kc_);

#define P1_CORE(AC)                                                                  \
    _Pragma("unroll") for (int mt_ = 0; mt_ < 2; ++mt_)                              \
    _Pragma("unroll") for (int kc_ = 0; kc_ < 4; ++kc_)                              \
        afr[mt_][kc_] = DS_A(AC, 2 + mt_, kc_);

#define MFMA16(MBASE)                                                                \
    __builtin_amdgcn_s_setprio(1);                                                   \
    _Pragma("unroll") for (int kc_ = 0; kc_ < 4; ++kc_)                              \
    _Pragma("unroll") for (int mt_ = 0; mt_ < 2; ++mt_)                              \
    _Pragma("unroll") for (int nt_ = 0; nt_ < 2; ++nt_)                              \
        acc[(MBASE) + mt_][nt_] = __builtin_amdgcn_mfma_f32_32x32x16_bf16(           \
            afr[mt_][kc_], bfr[nt_][kc_], acc[(MBASE) + mt_][nt_], 0, 0, 0);         \
    __builtin_amdgcn_s_setprio(0);                                                   \
    __builtin_amdgcn_sched_barrier(0);

#define TILE2(AC, BC, AO, KT)                                                        \
    P0_CORE(AC, BC);                                                                 \
    STAGE_A(AO, 0, (KT) + 64);  STAGE_A(AO, 128, (KT) + 64);                         \
    STAGE_A(AO, 64, (KT) + 64); STAGE_A(AO, 192, (KT) + 64);                         \
    BARRIER(); MFMA16(0); WAIT_VM(8); BARRIER();                                     \
    P1_CORE(AC);                                                                     \
    STAGE_B(BC, 0, (KT) + 128);  STAGE_B(BC, 64, (KT) + 128);                        \
    STAGE_B(BC, 128, (KT) + 128); STAGE_B(BC, 192, (KT) + 128);                      \
    BARRIER(); MFMA16(2); WAIT_VM(6); BARRIER();

__global__ __launch_bounds__(512, 2) void gemm256_kernel(
    const __bf16* __restrict__ Xb, const __bf16* __restrict__ Wt,
    const float* __restrict__ bias, float* __restrict__ out) {
    extern __shared__ __align__(16) char smem[];
    const int tid  = threadIdx.x;
    const int lane = tid & 63;
    const int wave = tid >> 6;
    const int wr = wave >> 2;   // 0..1
    const int wn = wave & 3;    // 0..3

    const int bid = blockIdx.x;
    const int wg = (bid & 7) * 128 + (bid >> 3);   // XCD swizzle, 1024 % 8 == 0
    const int m0 = (wg >> 4) * 256;
    const int n0 = (wg & 15) * 256;

    char* A0 = smem;
    char* B0 = smem + 32768;
    char* A1 = smem + 65536;
    char* B1 = smem + 98304;

    // staging constants: thread covers row (row0 + srow), 16B group (tid&7)
    const int srow = tid >> 3;
    const int scol = ((tid & 7) ^ (srow & 7)) << 3;   // inverse-swizzled source col (elems)
    const int sldsoff = wave * 1024;                  // wave-uniform LDS offset in chunk

    // frag-read constants: A row = wr*128 + mtG*32 + (lane&31); B phys = nt*128 + wn*32 + (lane&31)
    // swizzle XOR is lane-constant: (row&7) == (lane&7) for all frag rows.
    int colswk[4];
#pragma unroll
    for (int kc = 0; kc < 4; ++kc)
        colswk[kc] = ((kc * 16 + (lane >> 5) * 8) << 1) ^ ((lane & 7) << 4);
    const int aRow32 = (wr * 128 + (lane & 31)) * 128;
    const int bRow32 = (wn * 32 + (lane & 31)) * 128;

    f32x16 acc[4][2] = {};
    bf16x8 afr[2][4], bfr[2][4];

    // ---- prologue: B(0), A(0) [HT0 pair, HT1 pair], B(1); leave {A-HT1(0)x2, B(1)x4}
    STAGE_B(B0, 0, 0);   STAGE_B(B0, 64, 0);  STAGE_B(B0, 128, 0); STAGE_B(B0, 192, 0);
    STAGE_A(A0, 0, 0);   STAGE_A(A0, 128, 0);
    STAGE_A(A0, 64, 0);  STAGE_A(A0, 192, 0);
    STAGE_B(B1, 0, 64);  STAGE_B(B1, 64, 64); STAGE_B(B1, 128, 64); STAGE_B(B1, 192, 64);
    WAIT_VM(6);
    BARRIER();

    // ---- main loop: tiles 0..61 (A-stages reference t+1 <= 62, B-stages t+2 <= 63)
    for (int it = 0; it < 31; ++it) {
        const int kt = it * 128;
        TILE2(A0, B0, A1, kt);
        TILE2(A1, B1, A0, kt + 64);
    }

    // ---- tile 62 (A0/B0, kt=3968): stage only A(63); drain 8 -> 2
    P0_CORE(A0, B0);
    STAGE_A(A1, 0, 4032);  STAGE_A(A1, 128, 4032);
    STAGE_A(A1, 64, 4032); STAGE_A(A1, 192, 4032);
    BARRIER(); MFMA16(0); WAIT_VM(8); BARRIER();
    P1_CORE(A0);
    BARRIER(); MFMA16(2); WAIT_VM(2); BARRIER();

    // ---- tile 63 (A1/B1, kt=4032): no stages; drain to 0 before P1 reads
    P0_CORE(A1, B1);
    BARRIER(); MFMA16(0); WAIT_VM(0); BARRIER();
    P1_CORE(A1);
    BARRIER(); MFMA16(2);

    // ---- epilogue: 32x32 C/D map col=lane&31, row=(j&3)+8*(j>>2)+4*(lane>>5)
#pragma unroll
    for (int mtG = 0; mtG < 4; ++mtG) {
#pragma unroll
        for (int nt = 0; nt < 2; ++nt) {
            const int gc = n0 + wn * 64 + nt * 32 + (lane & 31);
            const float bv = bias[gc];
            const f32x16 a = acc[mtG][nt];
#pragma unroll
            for (int j = 0; j < 16; ++j) {
                const int row = (j & 3) + 8 * (j >> 2) + 4 * (lane >> 5);
                const int gr = m0 + wr * 128 + mtG * 32 + row;
                __builtin_nontemporal_store(a[j] + bv, &out[(size_t)gr * N_DIM + gc]);
            }
        }
    }
}

extern "C" void kernel_launch(void* const* d_in, const int* in_sizes, int n_in,
                              void* d_out, int out_size, void* d_ws, size_t ws_size,
                              hipStream_t stream) {
    const float* x    = (const float*)d_in[0];
    const float* W    = (const float*)d_in[1];
    const float* bias = (const float*)d_in[2];
    const float* lA   = (const float*)d_in[3];
    const float* lB   = (const float*)d_in[4];
    float* out = (float*)d_out;

    __bf16* Xb = (__bf16*)d_ws;
    __bf16* Wt = (__bf16*)((char*)d_ws + (size_t)M_DIM * K_DIM * 2);

    cast_x_kernel<<<2048, 256, 0, stream>>>(x, Xb, (size_t)M_DIM * K_DIM);
    prep_w_kernel<<<dim3(N_DIM / 32, K_DIM / 32), dim3(32, 8), 0, stream>>>(W, lA, lB, Wt);

    (void)hipFuncSetAttribute((const void*)gemm256_kernel,
                              hipFuncAttributeMaxDynamicSharedMemorySize, 131072);
    gemm256_kernel<<<1024, 512, 131072, stream>>>(Xb, Wt, bias, out);
}